// Round 6
// baseline (586.186 us; speedup 1.0000x reference)
//
#include <hip/hip_runtime.h>
#include <cstdint>

#define T_SEQ 40
#define NB    16384
#define NH    128
#define ZROW  136          // zeros row for exhausted spike streams (exact +0.0f)
#define NROWS 137          // 128 recurrent + 8 input + 1 zeros
#define ROWD  129          // staging writes lane-stride 129 -> bank-stride 1; reads lane-stride 1: conflict-free
#define WPB   16           // waves per block
#define NTHR  (WPB * 64)
#define NBLK  512          // 2 blocks/CU; each wave processes 2 batch rows INTERLEAVED

typedef float v2f __attribute__((ext_vector_type(2)));   // -> v_pk_*_f32

// ---- wave-wide sum of four floats via DPP (VALU pipe; keeps DS pipe free) ----
template <int C>
__device__ __forceinline__ float dppstep(float v) {
  int t = __builtin_amdgcn_update_dpp(0, __float_as_int(v), C, 0xF, 0xF, true);
  return v + __int_as_float(t);
}
#define WS4_STAGE(CTL) do { a = dppstep<CTL>(a); b = dppstep<CTL>(b); \
                            c = dppstep<CTL>(c); d = dppstep<CTL>(d); } while (0)
__device__ __forceinline__ void wave_sum4(float &a, float &b, float &c, float &d) {
  WS4_STAGE(0x111); WS4_STAGE(0x112); WS4_STAGE(0x114); WS4_STAGE(0x118);
  WS4_STAGE(0x142); WS4_STAGE(0x143);          // lane63 holds totals
  a = __int_as_float(__builtin_amdgcn_readlane(__float_as_int(a), 63));
  b = __int_as_float(__builtin_amdgcn_readlane(__float_as_int(b), 63));
  c = __int_as_float(__builtin_amdgcn_readlane(__float_as_int(c), 63));
  d = __int_as_float(__builtin_amdgcn_readlane(__float_as_int(d), 63));
}

// Spike iterator for one stream (E rows 0-63, O rows 64-127, I rows 128-135).
// Yields LDS dword offset of the weight row; zeros row when exhausted.
#define NEXTM(mE, mO, mI, dst) do {                                          \
    if (mE)      { dst = __builtin_ctzll(mE) * ROWD;        mE &= mE - 1; }  \
    else if (mO) { dst = (64 + __builtin_ctzll(mO)) * ROWD; mO &= mO - 1; }  \
    else if (mI) { dst = (128 + __builtin_ctzll(mI)) * ROWD; mI &= mI - 1; } \
    else dst = ZROW * ROWD;                                                  \
  } while (0)

__global__ __launch_bounds__(NTHR, 8)
void Policy_22033182228693_kernel(const float* __restrict__ x,
                                  const float* __restrict__ w_in,
                                  const float* __restrict__ w_rec,
                                  const float* __restrict__ w_out,
                                  const float* __restrict__ dmask,
                                  float* __restrict__ out)
{
  __shared__ float W[NROWS * ROWD];   // 70,692 B -> 2 blocks/CU = 32 waves

  const int tid = threadIdx.x;
  for (int e = tid; e < NH * NH; e += NTHR) {        // W[j][h] = w_rec[h][j]
    int h = e >> 7, j = e & 127;
    W[j * ROWD + h] = w_rec[e];
  }
  for (int e = tid; e < NH * 8; e += NTHR) {         // W[128+k][h] = w_in[h][k]
    int h = e >> 3, k = e & 7;
    W[(128 + k) * ROWD + h] = w_in[e];
  }
  for (int e = tid; e < ROWD; e += NTHR) W[ZROW * ROWD + e] = 0.f;   // zeros row
  __syncthreads();   // only barrier

  const int wave = tid >> 6;
  const int lane = tid & 63;   // lane owns neurons h=lane, h=lane+64
  const int gw   = blockIdx.x * WPB + wave;
  const int bA   = gw * 2, bB = gw * 2 + 1;

  // Readout weights (w_out shape (2,128)) — row-independent
  const float wo00 = w_out[lane];
  const float wo01 = w_out[lane + 64];
  const float wo10 = w_out[128 + lane];
  const float wo11 = w_out[192 + lane];

  const size_t TS = (size_t)NB * NH;

  // ---- per-row prologues ----
  float xvA = x[(size_t)bA * 4 + (lane & 3)];
  float xvB = x[(size_t)bB * 4 + (lane & 3)];
  float ccA = fmaxf(0.f, ((lane & 4) ? -50.f : 50.f) * xvA);
  float ccB = fmaxf(0.f, ((lane & 4) ? -50.f : 50.f) * xvB);
  if (lane >= 8) { ccA = 0.f; ccB = 0.f; }

  // Always-on channels (cc > 10 spike every step) folded into constants
  bool alwA = ccA > 10.f, alwB = ccB > 10.f;
  uint64_t aMA = __ballot((int)alwA);
  uint64_t aMB = __ballot((int)alwB);
  if (alwA) ccA = 0.f;
  if (alwB) ccB = 0.f;
  v2f cinA; cinA.x = 0.f; cinA.y = 0.f;
  v2f cinB; cinB.x = 0.f; cinB.y = 0.f;
  for (uint64_t m = aMA; m; m &= m - 1) {
    int o = (128 + __builtin_ctzll(m)) * ROWD;
    cinA.x += W[o + lane]; cinA.y += W[o + lane + 64];
  }
  for (uint64_t m = aMB; m; m &= m - 1) {
    int o = (128 + __builtin_ctzll(m)) * ROWD;
    cinB.x += W[o + lane]; cinB.y += W[o + lane + 64];
  }

  const float* gmA = dmask + (size_t)bA * NH;
  const float* gmB = dmask + (size_t)bB * NH;
  float mcA0 = gmA[lane],      mcA1 = gmA[lane + 64];
  float mcB0 = gmB[lane],      mcB1 = gmB[lane + 64];
  float mnA0 = gmA[TS + lane], mnA1 = gmA[TS + lane + 64];
  float mnB0 = gmB[TS + lane], mnB1 = gmB[TS + lane + 64];

  float veA = 0.f, veB = 0.f;
  v2f vA; vA.x = 0.f; vA.y = 0.f;   v2f vB; vB.x = 0.f; vB.y = 0.f;
  v2f iA; iA.x = 0.f; iA.y = 0.f;   v2f iB; iB.x = 0.f; iB.y = 0.f;
  float ioA0 = 0.f, ioA1 = 0.f, voA0 = 0.f, voA1 = 0.f;
  float ioB0 = 0.f, ioB1 = 0.f, voB0 = 0.f, voB1 = 0.f;
  float mA0 = -3.0e38f, mA1 = -3.0e38f, mB0 = -3.0e38f, mB1 = -3.0e38f;
  uint64_t bEA = 0, bOA = 0, bEB = 0, bOB = 0;

#pragma unroll 1
  for (int t = 0; t < T_SEQ; ++t) {
    // ---- encoders (slow channels only) ----
    veA += 0.1f * (ccA - veA);
    veB += 0.1f * (ccB - veB);
    bool ziA = veA > 1.0f, ziB = veB > 1.0f;
    if (ziA) veA = 0.f;
    if (ziB) veB = 0.f;
    uint64_t bIA = __ballot((int)ziA);
    uint64_t bIB = __ballot((int)ziB);

    // ---- hidden membranes (use old i) — packed, both rows ----
    v2f vdA = vA + 0.1f * (iA - vA);
    v2f vdB = vB + 0.1f * (iB - vB);
    bool zA0 = vdA.x > 1.0f, zA1 = vdA.y > 1.0f;
    bool zB0 = vdB.x > 1.0f, zB1 = vdB.y > 1.0f;
    vA.x = zA0 ? 0.f : vdA.x;  vA.y = zA1 ? 0.f : vdA.y;
    vB.x = zB0 ? 0.f : vdB.x;  vB.y = zB1 ? 0.f : vdB.y;

    // ---- fused 2-row sparse gather (prev z + current input spikes) ----
    v2f aA = 0.8f * iA;
    v2f aB = 0.8f * iB;
    {
      uint64_t mEA = bEA, mOA = bOA, mIA = bIA;
      uint64_t mEB = bEB, mOB = bOB, mIB = bIB;
      int nA = __popcll(mEA) + __popcll(mOA) + __popcll(mIA);
      int nB = __popcll(mEB) + __popcll(mOB) + __popcll(mIB);
      int n  = nA > nB ? nA : nB;
      if (n > 0) {
        // depth-2 priming per stream -> 4 ds_read2_b32 in flight
        int oA0, oB0, oA1, oB1;
        NEXTM(mEA, mOA, mIA, oA0);  NEXTM(mEB, mOB, mIB, oB0);
        NEXTM(mEA, mOA, mIA, oA1);  NEXTM(mEB, mOB, mIB, oB1);
        v2f pA0; pA0.x = W[oA0 + lane]; pA0.y = W[oA0 + lane + 64];
        v2f pB0; pB0.x = W[oB0 + lane]; pB0.y = W[oB0 + lane + 64];
        v2f pA1; pA1.x = W[oA1 + lane]; pA1.y = W[oA1 + lane + 64];
        v2f pB1; pB1.x = W[oB1 + lane]; pB1.y = W[oB1 + lane + 64];
#pragma unroll 1
        for (int k = 2; k < n; ++k) {
          int oA2, oB2;
          NEXTM(mEA, mOA, mIA, oA2);  NEXTM(mEB, mOB, mIB, oB2);
          v2f qA; qA.x = W[oA2 + lane]; qA.y = W[oA2 + lane + 64];
          v2f qB; qB.x = W[oB2 + lane]; qB.y = W[oB2 + lane + 64];
          aA += pA0;  aB += pB0;
          pA0 = pA1; pA1 = qA;
          pB0 = pB1; pB1 = qB;
        }
        aA += pA0;  aB += pB0;
        aA += pA1;  aB += pB1;
      }
      aA += cinA;  aB += cinB;
    }
    iA = aA;  iB = aB;

    // ballots for next step's recurrent input
    bEA = __ballot((int)zA0);  bOA = __ballot((int)zA1);
    bEB = __ballot((int)zB0);  bOB = __ballot((int)zB1);

    // ---- dropout + readout (both rows) ----
    float mtA0 = mcA0, mtA1 = mcA1, mtB0 = mcB0, mtB1 = mcB1;
    mcA0 = mnA0; mcA1 = mnA1; mcB0 = mnB0; mcB1 = mnB1;
    int tp = (t + 2 < T_SEQ) ? t + 2 : T_SEQ - 1;
    size_t so = (size_t)tp * TS;
    mnA0 = gmA[so + lane]; mnA1 = gmA[so + lane + 64];
    mnB0 = gmB[so + lane]; mnB1 = gmB[so + lane + 64];

    float zdA0 = zA0 ? mtA0 : 0.f, zdA1 = zA1 ? mtA1 : 0.f;
    float zdB0 = zB0 ? mtB0 : 0.f, zdB1 = zB1 ? mtB1 : 0.f;
    float uA0 = zdA0 * wo00 + zdA1 * wo01;
    float uA1 = zdA0 * wo10 + zdA1 * wo11;
    float uB0 = zdB0 * wo00 + zdB1 * wo01;
    float uB1 = zdB0 * wo10 + zdB1 * wo11;
    if (bEA | bOA | bEB | bOB) {
      wave_sum4(uA0, uA1, uB0, uB1);
    } else {
      uA0 = uA1 = uB0 = uB1 = 0.f;
    }

    voA0 += 0.1f * (ioA0 - voA0);  voA1 += 0.1f * (ioA1 - voA1);
    voB0 += 0.1f * (ioB0 - voB0);  voB1 += 0.1f * (ioB1 - voB1);
    ioA0 = 0.8f * ioA0 + uA0;      ioA1 = 0.8f * ioA1 + uA1;
    ioB0 = 0.8f * ioB0 + uB0;      ioB1 = 0.8f * ioB1 + uB1;
    mA0 = fmaxf(mA0, voA0);  mA1 = fmaxf(mA1, voA1);
    mB0 = fmaxf(mB0, voB0);  mB1 = fmaxf(mB1, voB1);
  }

  if (lane == 0) {
    float mxA = fmaxf(mA0, mA1);
    float eA0 = expf(mA0 - mxA), eA1 = expf(mA1 - mxA);
    float invA = 1.f / (eA0 + eA1);
    ((float2*)out)[bA] = make_float2(eA0 * invA, eA1 * invA);
    float mxB = fmaxf(mB0, mB1);
    float eB0 = expf(mB0 - mxB), eB1 = expf(mB1 - mxB);
    float invB = 1.f / (eB0 + eB1);
    ((float2*)out)[bB] = make_float2(eB0 * invB, eB1 * invB);
  }
}

extern "C" void kernel_launch(void* const* d_in, const int* in_sizes, int n_in,
                              void* d_out, int out_size, void* d_ws, size_t ws_size,
                              hipStream_t stream) {
  const float* x     = (const float*)d_in[0];
  const float* w_in  = (const float*)d_in[1];
  const float* w_rec = (const float*)d_in[2];
  const float* w_out = (const float*)d_in[3];
  const float* dmask = (const float*)d_in[4];
  float* out = (float*)d_out;

  hipLaunchKernelGGL(Policy_22033182228693_kernel, dim3(NBLK), dim3(NTHR), 0, stream,
                     x, w_in, w_rec, w_out, dmask, out);
}

// Round 7
// 506.094 us; speedup vs baseline: 1.1583x; 1.1583x over previous
//
#include <hip/hip_runtime.h>
#include <cstdint>

#define T_SEQ 40
#define NB    16384
#define NH    128
#define NROWS 136          // 128 recurrent rows + 8 input rows
#define ROWD  129          // staging writes lane-stride 129 -> bank-stride 1; reads lane-stride 1: conflict-free
#define WPB   16           // waves per block
#define NTHR  (WPB * 64)
#define NBLK  512          // 2 blocks/CU; each wave owns 2 batch rows (processed serially)

typedef float v2f __attribute__((ext_vector_type(2)));   // -> v_pk_*_f32

// ---- wave-wide sum of two floats via DPP (VALU pipe; keeps DS pipe free) ----
template <int C>
__device__ __forceinline__ float dppstep(float v) {
  int t = __builtin_amdgcn_update_dpp(0, __float_as_int(v), C, 0xF, 0xF, true);
  return v + __int_as_float(t);
}
__device__ __forceinline__ void wave_sum2(float &a, float &b) {
  a = dppstep<0x111>(a); b = dppstep<0x111>(b);   // row_shr:1
  a = dppstep<0x112>(a); b = dppstep<0x112>(b);   // row_shr:2
  a = dppstep<0x114>(a); b = dppstep<0x114>(b);   // row_shr:4
  a = dppstep<0x118>(a); b = dppstep<0x118>(b);   // row_shr:8
  a = dppstep<0x142>(a); b = dppstep<0x142>(b);   // row_bcast15
  a = dppstep<0x143>(a); b = dppstep<0x143>(b);   // row_bcast31 -> lane63 total
  a = __int_as_float(__builtin_amdgcn_readlane(__float_as_int(a), 63));
  b = __int_as_float(__builtin_amdgcn_readlane(__float_as_int(b), 63));
}

// rank = number of set bits of m strictly below this lane
__device__ __forceinline__ int lanerank(uint64_t m) {
  return __builtin_amdgcn_mbcnt_hi((unsigned int)(m >> 32),
         __builtin_amdgcn_mbcnt_lo((unsigned int)m, 0));
}

__global__ __launch_bounds__(NTHR, 8)
void Policy_22033182228693_kernel(const float* __restrict__ x,
                                  const float* __restrict__ w_in,
                                  const float* __restrict__ w_rec,
                                  const float* __restrict__ w_out,
                                  const float* __restrict__ dmask,
                                  float* __restrict__ out)
{
  __shared__ float W[NROWS * ROWD];     // 70,176 B
  __shared__ int   Cbuf[WPB * 64];      // 4,096 B  -> total 74,272 B: still 2 blocks/CU

  const int tid = threadIdx.x;
  for (int e = tid; e < NH * NH; e += NTHR) {        // W[j][h] = w_rec[h][j]
    int h = e >> 7, j = e & 127;
    W[j * ROWD + h] = w_rec[e];
  }
  for (int e = tid; e < NH * 8; e += NTHR) {         // W[128+k][h] = w_in[h][k]
    int h = e >> 3, k = e & 7;
    W[(128 + k) * ROWD + h] = w_in[e];
  }
  __syncthreads();   // only barrier

  const int wave = tid >> 6;
  const int lane = tid & 63;               // lane owns neurons h=lane, h=lane+64
  const int gw   = blockIdx.x * WPB + wave;
  int* const Cw  = Cbuf + wave * 64;       // per-wave compact array (no barriers needed)

  // Per-lane constant row offsets (dword units) for the three spike streams
  const int offE = lane * ROWD;            // recurrent neuron h=lane        -> row lane
  const int offO = (64 + lane) * ROWD;     // recurrent neuron h=lane+64     -> row 64+lane
  const int offI = (128 + lane) * ROWD;    // input channel lane (lanes 0-7) -> row 128+lane

  // Readout weights (w_out shape (2,128))
  const float wo00 = w_out[lane];
  const float wo01 = w_out[lane + 64];
  const float wo10 = w_out[128 + lane];
  const float wo11 = w_out[192 + lane];

  const size_t TS = (size_t)NB * NH;

#pragma unroll 1
  for (int rr = 0; rr < 2; ++rr) {
    const int b = gw * 2 + rr;

    // ---- per-row prologue ----
    float xv = x[(size_t)b * 4 + (lane & 3)];
    float cc = fmaxf(0.f, ((lane & 4) ? -50.f : 50.f) * xv);
    if (lane >= 8) cc = 0.f;

    // Channels with cc > 10 spike EVERY step; fold their w_in rows into a constant.
    bool always = cc > 10.f;
    uint64_t aM = __ballot((int)always);
    if (always) cc = 0.f;
    v2f cin; cin.x = 0.f; cin.y = 0.f;
    for (uint64_t m = aM; m; m &= m - 1) {
      int o = (128 + __builtin_ctzll(m)) * ROWD;
      cin.x += W[o + lane];
      cin.y += W[o + lane + 64];
    }

    const float* gmu = dmask + (size_t)b * NH;
    float mc0 = gmu[lane],      mc1 = gmu[lane + 64];
    float mn0 = gmu[TS + lane], mn1 = gmu[TS + lane + 64];

    float ve = 0.f;
    v2f v;  v.x = 0.f;  v.y = 0.f;
    v2f i;  i.x = 0.f;  i.y = 0.f;
    float io0 = 0.f, io1 = 0.f, vo0 = 0.f, vo1 = 0.f;
    float m0 = -3.0e38f, m1 = -3.0e38f;
    uint64_t bE = 0, bO = 0;

#pragma unroll 1
    for (int t = 0; t < T_SEQ; ++t) {
      // ---- encoder (slow channels only) ----
      ve += 0.1f * (cc - ve);
      bool zi = ve > 1.0f;
      if (zi) ve = 0.f;
      uint64_t bI = __ballot((int)zi);

      // ---- hidden membrane (uses old i) — packed ----
      v2f vd = v + 0.1f * (i - v);
      bool z0 = vd.x > 1.0f, z1 = vd.y > 1.0f;
      v.x = z0 ? 0.f : vd.x;
      v.y = z1 ? 0.f : vd.y;

      // ---- parallel spike compaction: rank via mbcnt, scatter row offsets ----
      // Order: E rows (h=lane spikes of prev step), then O rows, then I rows.
      int pE = __popcll(bE), pO = __popcll(bO), pI = __popcll(bI);
      int n  = pE + pO + pI;
      bool sE = (bE >> lane) & 1;          // this lane's prev-step z0
      bool sO = (bO >> lane) & 1;          // this lane's prev-step z1
      if (sE) Cw[lanerank(bE)] = offE;
      if (sO) Cw[pE + lanerank(bO)] = offO;
      if (zi) Cw[pE + pO + lanerank(bI)] = offI;
      int cv = Cw[lane];                   // compacted offsets, entry k in lane k

      // ---- synaptic current: decay + gather (iterations fully independent) ----
      v2f a = 0.8f * i;
      {
        int k = 0;
#pragma unroll 1
        for (; k + 2 <= n; k += 2) {
          int o0 = __builtin_amdgcn_readlane(cv, k);
          int o1 = __builtin_amdgcn_readlane(cv, k + 1);
          v2f w0; w0.x = W[o0 + lane]; w0.y = W[o0 + lane + 64];
          v2f w1; w1.x = W[o1 + lane]; w1.y = W[o1 + lane + 64];
          a += w0;
          a += w1;
        }
        if (k < n) {
          int o0 = __builtin_amdgcn_readlane(cv, k);
          v2f w0; w0.x = W[o0 + lane]; w0.y = W[o0 + lane + 64];
          a += w0;
        }
        a += cin;    // always-on input contribution
      }
      i = a;

      // ballots for next step's recurrent input
      bE = __ballot((int)z0);
      bO = __ballot((int)z1);

      // ---- dropout + readout ----
      float mt0 = mc0, mt1 = mc1;
      mc0 = mn0; mc1 = mn1;
      int tp = (t + 2 < T_SEQ) ? t + 2 : T_SEQ - 1;
      size_t so = (size_t)tp * TS;
      mn0 = gmu[so + lane];
      mn1 = gmu[so + lane + 64];

      float zd0 = z0 ? mt0 : 0.f;
      float zd1 = z1 ? mt1 : 0.f;
      float u0 = zd0 * wo00 + zd1 * wo01;
      float u1 = zd0 * wo10 + zd1 * wo11;
      if (bE | bO) {
        wave_sum2(u0, u1);
      } else {
        u0 = 0.f; u1 = 0.f;
      }

      vo0 += 0.1f * (io0 - vo0);
      vo1 += 0.1f * (io1 - vo1);
      io0 = 0.8f * io0 + u0;
      io1 = 0.8f * io1 + u1;
      m0 = fmaxf(m0, vo0);
      m1 = fmaxf(m1, vo1);
    }

    if (lane == 0) {
      float mx = fmaxf(m0, m1);
      float e0 = expf(m0 - mx), e1 = expf(m1 - mx);
      float inv = 1.f / (e0 + e1);
      ((float2*)out)[b] = make_float2(e0 * inv, e1 * inv);
    }
  }
}

extern "C" void kernel_launch(void* const* d_in, const int* in_sizes, int n_in,
                              void* d_out, int out_size, void* d_ws, size_t ws_size,
                              hipStream_t stream) {
  const float* x     = (const float*)d_in[0];
  const float* w_in  = (const float*)d_in[1];
  const float* w_rec = (const float*)d_in[2];
  const float* w_out = (const float*)d_in[3];
  const float* dmask = (const float*)d_in[4];
  float* out = (float*)d_out;

  hipLaunchKernelGGL(Policy_22033182228693_kernel, dim3(NBLK), dim3(NTHR), 0, stream,
                     x, w_in, w_rec, w_out, dmask, out);
}